// Round 9
// baseline (941.013 us; speedup 1.0000x reference)
//
#include <hip/hip_runtime.h>
#include <hip/hip_bf16.h>

// LinearStateSpace via truncated convolution:
//   y_t = D u_t + sum_{d=1..96} (C A^{d-1} B) u_{t-d},  rho(A)=0.9 -> tail ~4e-4.
// Precompute: ONE persistent kernel (256 WGs, software grid barriers), 8-level
// bf16x2 (hi+lo, 3-term) GEMM chain. Single A-power chain: each squaring writes
// rm AND cm (LDS-transposed epilogue), so Y_s = X_s^T is free. K-loop: 2x64KB
// LDS double buffer, 1-deep prefetch, counted s_waitcnt vmcnt(16) (T3+T4).
// Main conv: 128x128 MFMA GEMM, sliding-window A, XOR-swizzled LDS,
// double-buffered counted vmcnt(8).

#define NSTEPS 32768
#define LTRUNC 96
#define NDBLK  (LTRUNC + 1)
#define KTOT   (NDBLK * 128)     // 12416
#define SPLITK 4                 // conv split-K

typedef __attribute__((ext_vector_type(8))) short short8;
typedef __attribute__((ext_vector_type(4))) float f32x4;
typedef __hip_bfloat16 bf16;

// ---- ws layout (bf16-element offsets) ----
#define ME 1048576
#define O_AHR 0
#define O_ALR (1*ME)
#define O_AHC (2*ME)
#define O_ALC (3*ME)
#define O_XPH (4*ME)
#define O_XPL (5*ME)
#define O_XQH (6*ME)
#define O_XQL (7*ME)
#define O_YPH (8*ME)
#define O_YPL (9*ME)
#define O_YQH (10*ME)
#define O_YQL (11*ME)
#define O_GH  (12*ME)                   // 2048 x 1024 (G_j = C A^j, j=0..15)
#define O_GL  (14*ME)
#define O_RTH (16*ME)                   // Rt = R^T rows, 6 blocks of 128 x 1024
#define O_RTL (O_RTH + 917504)
#define O_KBT (O_RTL + 917504)          // 128 x KTOT
#define O_UBF (O_KBT + 128*KTOT)        // (LTRUNC+NSTEPS) x 128
#define WS_ELEMS ((size_t)O_UBF + (size_t)(LTRUNC + NSTEPS) * 128)
#define O_BAR_BYTES ((WS_ELEMS * 2 + 255) & ~(size_t)255)

__device__ __forceinline__ void gload16(const void* g, void* l) {
  __builtin_amdgcn_global_load_lds(
      (const __attribute__((address_space(1))) void*)g,
      (__attribute__((address_space(3))) void*)l, 16, 0, 0);
}

__device__ __forceinline__ void split1(float x, bf16& h, bf16& l) {
  h = __float2bfloat16(x);
  l = __float2bfloat16(x - __bfloat162float(h));
}

// ---------- f32 -> (hi,lo) bf16, row-major ----------
__global__ __launch_bounds__(256) void split_rm(const float* __restrict__ src,
                                                bf16* __restrict__ hi, bf16* __restrict__ lo) {
  const int i = (blockIdx.x * 256 + threadIdx.x) * 4;
  const float4 v = *reinterpret_cast<const float4*>(src + i);
  const float vv[4] = {v.x, v.y, v.z, v.w};
#pragma unroll
  for (int j = 0; j < 4; ++j) { bf16 h, l; split1(vv[j], h, l); hi[i + j] = h; lo[i + j] = l; }
}

// ---------- f32 (RxC) -> (hi,lo) bf16 transposed (CxR) ----------
__global__ __launch_bounds__(256) void split_cm(const float* __restrict__ src,
                                                bf16* __restrict__ hi, bf16* __restrict__ lo,
                                                int R, int C) {
  __shared__ float t[64][65];
  const int r0 = blockIdx.y << 6, c0 = blockIdx.x << 6;
  const int tid = threadIdx.x;
#pragma unroll
  for (int i = 0; i < 16; ++i) {
    const int e = i * 256 + tid, rl = e >> 6, cl = e & 63;
    t[rl][cl] = src[(size_t)(r0 + rl) * C + c0 + cl];
  }
  __syncthreads();
#pragma unroll
  for (int i = 0; i < 16; ++i) {
    const int e = i * 256 + tid, cl = e >> 6, rl = e & 63;
    bf16 h, l; split1(t[rl][cl], h, l);
    hi[(size_t)(c0 + cl) * R + r0 + rl] = h;
    lo[(size_t)(c0 + cl) * R + r0 + rl] = l;
  }
}

// ---------- input transpose: inp(128 x 32768) -> Ubf bf16 (LTRUNC+32768) x 128 ----------
__global__ __launch_bounds__(256) void ubuild(const float* __restrict__ inp, bf16* __restrict__ Ubf) {
  __shared__ float tile[64][65];
  const int t0 = blockIdx.x << 6, s0 = blockIdx.y << 6;
  const int tid = threadIdx.x;
#pragma unroll
  for (int i = 0; i < 16; ++i) {
    const int e = i * 256 + tid, sl = e >> 6, tl = e & 63;
    tile[sl][tl] = inp[(size_t)(s0 + sl) * NSTEPS + t0 + tl];
  }
  __syncthreads();
#pragma unroll
  for (int i = 0; i < 16; ++i) {
    const int e = i * 256 + tid, tl = e >> 6, sl = e & 63;
    Ubf[(size_t)(LTRUNC + t0 + tl) * 128 + s0 + sl] = __float2bfloat16(tile[sl][tl]);
  }
}

// ---------- Kbt d=0 block = bf16(D) ----------
__global__ __launch_bounds__(256) void dinit(const float* __restrict__ Dw, bf16* __restrict__ Kbt) {
  const int e = blockIdx.x * 256 + threadIdx.x;   // 16384
  const int r = e >> 7, s = e & 127;
  Kbt[(size_t)r * KTOT + s] = __float2bfloat16(Dw[e]);
}

// ---------- persistent chain mega-kernel ----------
// Every GEMM: C = (Ah+Al)(Bh+Bl), A rm MxK(1024), B = rm rows of right-factor^T,
// per-WG one 128x128 tile, out rm hi/lo (+ optional transposed hi/lo) or Kbt.
struct Job { int ah, al, bh, bl, oh, ol, oth, otl, mt, nt, dbase; };
__device__ const Job JOBS[19] = {
  // L1: X1=A^2 (also Y1=X1^T), G1=G0*A
  {O_AHR,O_ALR,O_AHC,O_ALC, O_XPH,O_XPL, O_YPH,O_YPL, 8,8,-1},
  {O_GH, O_GL, O_AHC,O_ALC, O_GH+131072,O_GL+131072, -1,-1, 1,8,-1},
  // L2: X2 (+Y2), G2-3 (B=Y1)
  {O_XPH,O_XPL,O_YPH,O_YPL, O_XQH,O_XQL, O_YQH,O_YQL, 8,8,-1},
  {O_GH, O_GL, O_YPH,O_YPL, O_GH+262144,O_GL+262144, -1,-1, 2,8,-1},
  // L3: X3 (+Y3), G4-7 (B=Y2)
  {O_XQH,O_XQL,O_YQH,O_YQL, O_XPH,O_XPL, O_YPH,O_YPL, 8,8,-1},
  {O_GH, O_GL, O_YQH,O_YQL, O_GH+524288,O_GL+524288, -1,-1, 4,8,-1},
  // L4: X4=A^16 (+Y4), G8-15 (B=Y3)
  {O_XPH,O_XPL,O_YPH,O_YPL, O_XQH,O_XQL, O_YQH,O_YQL, 8,8,-1},
  {O_GH, O_GL, O_YPH,O_YPL, O_GH+1048576,O_GL+1048576, -1,-1, 8,8,-1},
  // L5: X5=A^32 (+Y5), Rt1=Rt0*Y4 (B-op = X4 rows)
  {O_XQH,O_XQL,O_YQH,O_YQL, O_XPH,O_XPL, O_YPH,O_YPL, 8,8,-1},
  {O_RTH,O_RTL,O_XQH,O_XQL, O_RTH+131072,O_RTL+131072, -1,-1, 1,8,-1},
  // L6: X6=A^64 (rm only), Rt2-3=Rt0-1*Y5 (B-op = X5 rows)
  {O_XPH,O_XPL,O_YPH,O_YPL, O_XQH,O_XQL, -1,-1, 8,8,-1},
  {O_RTH,O_RTL,O_XPH,O_XPL, O_RTH+262144,O_RTL+262144, -1,-1, 2,8,-1},
  // L7: Rt4-5=Rt0-1*Y6 (B-op = X6 rows); K m=0..3 (B=Rt_m)
  {O_RTH,O_RTL,O_XQH,O_XQL, O_RTH+524288,O_RTL+524288, -1,-1, 2,8,-1},
  {O_GH,O_GL, O_RTH,        O_RTL,        O_KBT,0, -1,-1, 16,1, 1},
  {O_GH,O_GL, O_RTH+131072, O_RTL+131072, O_KBT,0, -1,-1, 16,1, 17},
  {O_GH,O_GL, O_RTH+262144, O_RTL+262144, O_KBT,0, -1,-1, 16,1, 33},
  {O_GH,O_GL, O_RTH+393216, O_RTL+393216, O_KBT,0, -1,-1, 16,1, 49},
  // L8: K m=4..5
  {O_GH,O_GL, O_RTH+524288, O_RTL+524288, O_KBT,0, -1,-1, 16,1, 65},
  {O_GH,O_GL, O_RTH+655360, O_RTL+655360, O_KBT,0, -1,-1, 16,1, 81},
};
__device__ const int LVL[9] = {0,2,4,6,8,10,12,17,19};

__global__ __launch_bounds__(256) void chain_mega(bf16* __restrict__ ws, int* __restrict__ bar)
{
  // 128KB: 2 pipeline buffers of 64KB (4 tiles x 16KB: Ah@0 Al@16K Bh@32K Bl@48K).
  // Aliased as 128x129 f32 transpose tile (66KB) in the epilogue (after K-loop).
  __shared__ __align__(16) char smem[131072];
  const int tid = threadIdx.x, lane = tid & 63, wave = tid >> 6;
  const int wm = wave & 1, wn = wave >> 1, l15 = lane & 15, lk = lane >> 4;
  const int srow = tid >> 3, sc8 = (tid & 7) << 3;
  const int g8 = (((tid & 7) ^ (srow & 7)) << 3);           // pre-swizzled source chunk
  const int ca0 = ((lk ^ (l15 & 7)) << 3);                  // swizzled read offs, kh=0
  const int ca1 = (((4 + lk) ^ (l15 & 7)) << 3);            // kh=1

  for (int lvl = 0; lvl < 8; ++lvl) {
    int idx = blockIdx.x;
    int j = LVL[lvl];
    const int je = LVL[lvl + 1];
    while (j < je && idx >= JOBS[j].mt * JOBS[j].nt) { idx -= JOBS[j].mt * JOBS[j].nt; ++j; }
    if (j < je) {
      const Job job = JOBS[j];
      const int my = idx / job.nt, nx = idx - my * job.nt;
      const int m0 = my << 7, n0 = nx << 7;
      const bf16* Ah = ws + job.ah; const bf16* Al = ws + job.al;
      const bf16* Bh = ws + job.bh; const bf16* Bl = ws + job.bl;
      f32x4 acc[4][4] = {};

      // stage K-chunk ks (64 cols) into buffer buf: 16 global_load_lds / thread
      auto stage = [&](int ks, int buf) {
        char* base = smem + buf * 65536;
        const int k0 = ks << 6;
#pragma unroll
        for (int p = 0; p < 4; ++p) {
          const int row = (p << 5) + srow;
          const int loff = row * 128 + (sc8 << 1);          // bytes within 16KB tile
          const size_t aoff = (size_t)(m0 + row) * 1024 + k0 + g8;
          const size_t boff = (size_t)(n0 + row) * 1024 + k0 + g8;
          gload16(Ah + aoff, base + loff);
          gload16(Al + aoff, base + 16384 + loff);
          gload16(Bh + boff, base + 32768 + loff);
          gload16(Bl + boff, base + 49152 + loff);
        }
      };

      stage(0, 0);                                          // prologue: 16 in flight
      for (int ks = 0; ks < 16; ++ks) {
        if (ks + 1 < 16) {
          stage(ks + 1, (ks + 1) & 1);                      // +16 -> 32 in flight
          asm volatile("s_waitcnt vmcnt(16)" ::: "memory"); // stage ks landed
        } else {
          asm volatile("s_waitcnt vmcnt(0)" ::: "memory");
        }
        __builtin_amdgcn_s_barrier();                       // all waves' loads landed
        __builtin_amdgcn_sched_barrier(0);
        {
          char* base = smem + (ks & 1) * 65536;
          const bf16* pAh = (const bf16*)(base);
          const bf16* pAl = (const bf16*)(base + 16384);
          const bf16* pBh = (const bf16*)(base + 32768);
          const bf16* pBl = (const bf16*)(base + 49152);
#pragma unroll
          for (int kh = 0; kh < 2; ++kh) {
            const int cb = kh ? ca1 : ca0;
            short8 ah[4], al[4], bh[4], bl[4];
#pragma unroll
            for (int mi = 0; mi < 4; ++mi) {
              const int r = ((wm << 6) + (mi << 4) + l15) * 64 + cb;
              ah[mi] = *reinterpret_cast<const short8*>(pAh + r);
              al[mi] = *reinterpret_cast<const short8*>(pAl + r);
            }
#pragma unroll
            for (int ni = 0; ni < 4; ++ni) {
              const int r = ((wn << 6) + (ni << 4) + l15) * 64 + cb;
              bh[ni] = *reinterpret_cast<const short8*>(pBh + r);
              bl[ni] = *reinterpret_cast<const short8*>(pBl + r);
            }
#pragma unroll
            for (int mi = 0; mi < 4; ++mi)
#pragma unroll
              for (int ni = 0; ni < 4; ++ni) {
                acc[mi][ni] = __builtin_amdgcn_mfma_f32_16x16x32_bf16(ah[mi], bh[ni], acc[mi][ni], 0, 0, 0);
                acc[mi][ni] = __builtin_amdgcn_mfma_f32_16x16x32_bf16(ah[mi], bl[ni], acc[mi][ni], 0, 0, 0);
                acc[mi][ni] = __builtin_amdgcn_mfma_f32_16x16x32_bf16(al[mi], bh[ni], acc[mi][ni], 0, 0, 0);
              }
          }
        }
        __builtin_amdgcn_sched_barrier(0);
        __builtin_amdgcn_s_barrier();                       // buf[(ks+1)&1^1] free for restage
      }

      // ---- epilogue: C/D layout col = lane&15, row = 4*(lane>>4)+reg ----
      if (job.dbase >= 0) {
        bf16* kb = ws + job.oh;
        const int d = job.dbase + my;
#pragma unroll
        for (int mi = 0; mi < 4; ++mi)
#pragma unroll
          for (int ni = 0; ni < 4; ++ni) {
            const int cl = (wn << 6) + (ni << 4) + l15;
#pragma unroll
            for (int rg = 0; rg < 4; ++rg) {
              const int rl = (wm << 6) + (mi << 4) + (lk << 2) + rg;
              bf16 h, l; split1(acc[mi][ni][rg], h, l);
              kb[(size_t)rl * KTOT + (size_t)d * 128 + cl] = h;
            }
          }
      } else {
        bf16* oh = ws + job.oh; bf16* ol = ws + job.ol;
#pragma unroll
        for (int mi = 0; mi < 4; ++mi)
#pragma unroll
          for (int ni = 0; ni < 4; ++ni) {
            const int cl = (wn << 6) + (ni << 4) + l15;
#pragma unroll
            for (int rg = 0; rg < 4; ++rg) {
              const int rl = (wm << 6) + (mi << 4) + (lk << 2) + rg;
              bf16 h, l; split1(acc[mi][ni][rg], h, l);
              oh[(size_t)(m0 + rl) * 1024 + n0 + cl] = h;
              ol[(size_t)(m0 + rl) * 1024 + n0 + cl] = l;
            }
          }
        if (job.oth >= 0) {                                 // transposed copy via LDS
          float* tT = (float*)smem;                         // 128 x 129 f32 (66KB)
#pragma unroll
          for (int mi = 0; mi < 4; ++mi)
#pragma unroll
            for (int ni = 0; ni < 4; ++ni) {
              const int cl = (wn << 6) + (ni << 4) + l15;
#pragma unroll
              for (int rg = 0; rg < 4; ++rg) {
                const int rl = (wm << 6) + (mi << 4) + (lk << 2) + rg;
                tT[rl * 129 + cl] = acc[mi][ni][rg];
              }
            }
          __syncthreads();
          bf16* yh = ws + job.oth; bf16* yl = ws + job.otl;
#pragma unroll
          for (int i = 0; i < 64; ++i) {
            const int e = i * 256 + tid, yr = e >> 7, yc = e & 127;
            bf16 h, l; split1(tT[yc * 129 + yr], h, l);
            yh[(size_t)(n0 + yr) * 1024 + m0 + yc] = h;
            yl[(size_t)(n0 + yr) * 1024 + m0 + yc] = l;
          }
        }
      }
    }
    // ---- device-scope grid barrier (256 WGs, 1/CU via 128KB LDS: co-resident) ----
    __syncthreads();
    if (tid == 0) {
      __hip_atomic_fetch_add(bar, 1, __ATOMIC_RELEASE, __HIP_MEMORY_SCOPE_AGENT);
      const int target = 256 * (lvl + 1);
      while (__hip_atomic_load(bar, __ATOMIC_ACQUIRE, __HIP_MEMORY_SCOPE_AGENT) < target)
        __builtin_amdgcn_s_sleep(8);
    }
    __syncthreads();
  }
}

// ---------- main conv: out(32768x128) += A_virt @ Kbt, split-K ----------
__global__ __launch_bounds__(256) void conv_mfma(
    const bf16* __restrict__ Ubf, const bf16* __restrict__ Kbt, float* __restrict__ out)
{
  __shared__ __align__(16) bf16 As[2][128 * 64];
  __shared__ __align__(16) bf16 Bs[2][128 * 64];
  const int tid = threadIdx.x;
  const int t0 = blockIdx.x << 7;
  const int lane = tid & 63, wave = tid >> 6;
  const int wm = wave & 1, wn = wave >> 1;
  const int l15 = lane & 15, lk = lane >> 4;
  const int srow = tid >> 3, sc8 = (tid & 7) << 3;
  const int g8 = (((tid & 7) ^ (srow & 7)) << 3);
  const int ca0 = ((lk ^ (l15 & 7)) << 3);
  const int ca1 = (((4 + lk) ^ (l15 & 7)) << 3);
  const int ntot = KTOT / 64;                       // 194
  const int sb = (blockIdx.y * ntot) / SPLITK;
  const int se = ((blockIdx.y + 1) * ntot) / SPLITK;
  f32x4 acc[4][4] = {};

  auto stage = [&](int it, int buf) {
    const int kk0 = it << 6;
    const int d = kk0 >> 7, s0 = kk0 & 127;
    const bf16* srcA = Ubf + (size_t)(LTRUNC + t0 - d) * 128 + s0;
    const bf16* srcB = Kbt + kk0;
#pragma unroll
    for (int p = 0; p < 4; ++p) {
      const int row = (p << 5) + srow;
      gload16(srcA + (size_t)row * 128 + g8, &As[buf][row * 64 + sc8]);
      gload16(srcB + (size_t)row * KTOT + g8, &Bs[buf][row * 64 + sc8]);
    }
  };

  stage(sb, 0);
  int cur = 0;
  for (int it = sb; it < se; ++it) {
    if (it + 1 < se) {
      stage(it + 1, cur ^ 1);
      asm volatile("s_waitcnt vmcnt(8)" ::: "memory");
    } else {
      asm volatile("s_waitcnt vmcnt(0)" ::: "memory");
    }
    __builtin_amdgcn_s_barrier();
    __builtin_amdgcn_sched_barrier(0);
#pragma unroll
    for (int kh = 0; kh < 2; ++kh) {
      const int cb = kh ? ca1 : ca0;
      short8 a[4], b[4];
#pragma unroll
      for (int mi = 0; mi < 4; ++mi)
        a[mi] = *reinterpret_cast<const short8*>(&As[cur][((wm << 6) + (mi << 4) + l15) * 64 + cb]);
#pragma unroll
      for (int ni = 0; ni < 4; ++ni)
        b[ni] = *reinterpret_cast<const short8*>(&Bs[cur][((wn << 6) + (ni << 4) + l15) * 64 + cb]);
#pragma unroll
      for (int mi = 0; mi < 4; ++mi)
#pragma unroll
        for (int ni = 0; ni < 4; ++ni)
          acc[mi][ni] = __builtin_amdgcn_mfma_f32_16x16x32_bf16(a[mi], b[ni], acc[mi][ni], 0, 0, 0);
    }
    __builtin_amdgcn_sched_barrier(0);
    __builtin_amdgcn_s_barrier();
    cur ^= 1;
  }
#pragma unroll
  for (int mi = 0; mi < 4; ++mi)
#pragma unroll
    for (int ni = 0; ni < 4; ++ni) {
      const int rcol = (wn << 6) + (ni << 4) + l15;
#pragma unroll
      for (int rg = 0; rg < 4; ++rg) {
        const int t = t0 + (wm << 6) + (mi << 4) + (lk << 2) + rg;
        atomicAdd(out + (size_t)t * 128 + rcol, acc[mi][ni][rg]);
      }
    }
}

extern "C" void kernel_launch(void* const* d_in, const int* in_sizes, int n_in,
                              void* d_out, int out_size, void* d_ws, size_t ws_size,
                              hipStream_t stream)
{
  const float* inp = (const float*)d_in[0];
  const float* Aw  = (const float*)d_in[1];
  const float* Bw  = (const float*)d_in[2];
  const float* Cw  = (const float*)d_in[3];
  const float* Dw  = (const float*)d_in[4];
  float* out = (float*)d_out;
  (void)in_sizes; (void)n_in; (void)out_size; (void)ws_size;

  bf16* W = (bf16*)d_ws;
  int* bar = (int*)((char*)d_ws + O_BAR_BYTES);

  // ---- pre-passes (independent, small) ----
  hipMemsetAsync(W + O_UBF, 0, (size_t)LTRUNC * 128 * 2, stream);       // Ubf pad rows
  ubuild<<<dim3(NSTEPS / 64, 2), 256, 0, stream>>>(inp, W + O_UBF);
  split_rm<<<1024, 256, 0, stream>>>(Aw, W + O_AHR, W + O_ALR);          // X0 = A rm
  split_cm<<<dim3(16, 16), 256, 0, stream>>>(Aw, W + O_AHC, W + O_ALC, 1024, 1024); // A^T rm
  split_rm<<<128, 256, 0, stream>>>(Cw, W + O_GH, W + O_GL);             // G_0 = C
  split_cm<<<dim3(2, 16), 256, 0, stream>>>(Bw, W + O_RTH, W + O_RTL, 1024, 128);   // Rt_0 = B^T
  dinit<<<64, 256, 0, stream>>>(Dw, W + O_KBT);                          // K_0 = D
  hipMemsetAsync(bar, 0, 256, stream);                                   // grid-barrier counter

  // ---- entire 8-level precompute chain in one persistent dispatch ----
  chain_mega<<<256, 256, 0, stream>>>(W, bar);

  // ---- main truncated convolution ----
  hipMemsetAsync(out, 0, (size_t)NSTEPS * 128 * 4, stream);
  conv_mfma<<<dim3(NSTEPS / 128, SPLITK), 256, 0, stream>>>(W + O_UBF, W + O_KBT, out);
}